// Round 6
// baseline (373.002 us; speedup 1.0000x reference)
//
#include <hip/hip_runtime.h>
#include <hip/hip_bf16.h>

// QuantizedLinear: out[8192,4096] = x[8192,4096] @ W^T + bias
//   W[n,k] = codebooks[codes[n, k/8]][k%8] * scales[n]  (NCB=1; scale folded into epilogue)
// Round-6 GEMM: LDS-traffic reduction. B fragments load DIRECTLY global->VGPR
// (B was only 2-way shared; frag layout is a native per-lane 16B global pattern),
// removing 1/3 of LDS reads and ALL B staging writes. LDS holds A only:
// 3 slots x 32 KiB, staged 2 groups ahead. 2 barriers/group, counted vmcnt
// over the mixed {A-stage, B-load} queue.
#define M_DIM 8192
#define N_DIM 4096
#define K_DIM 4096
#define NOG 4096
#define NIG 512

typedef __bf16 bf16x8 __attribute__((ext_vector_type(8)));
typedef float f32x4 __attribute__((ext_vector_type(4)));
typedef short short8 __attribute__((ext_vector_type(8)));

typedef const __attribute__((address_space(1))) void* as1_cvoid_p;
typedef __attribute__((address_space(3))) void* as3_void_p;

__device__ __forceinline__ unsigned short f2bf(float f) {
  union { float f; unsigned u; } c; c.f = f;
  unsigned u = c.u;
  return (unsigned short)((u + 0x7fffu + ((u >> 16) & 1u)) >> 16);
}

// ---- Kernel 1: x f32 -> bf16
__global__ __launch_bounds__(256) void cvt_x_kernel(const float* __restrict__ x,
                                                    unsigned short* __restrict__ xb,
                                                    int n8) {
  int i = blockIdx.x * blockDim.x + threadIdx.x;
  int stride = gridDim.x * blockDim.x;
  for (; i < n8; i += stride) {
    const float4* p = (const float4*)(x) + (size_t)i * 2;
    float4 a = p[0], b = p[1];
    short8 o;
    o[0] = (short)f2bf(a.x); o[1] = (short)f2bf(a.y);
    o[2] = (short)f2bf(a.z); o[3] = (short)f2bf(a.w);
    o[4] = (short)f2bf(b.x); o[5] = (short)f2bf(b.y);
    o[6] = (short)f2bf(b.z); o[7] = (short)f2bf(b.w);
    ((short8*)xb)[i] = o;
  }
}

// ---- Kernel 2: gather-dequant -> bf16 W [N][K]
__global__ __launch_bounds__(256) void dequant_kernel(const int* __restrict__ codes,
                                                      const float* __restrict__ cb,
                                                      unsigned short* __restrict__ wb) {
  int idx = blockIdx.x * blockDim.x + threadIdx.x;
  int code = codes[idx];
  const float4* p = (const float4*)(cb + (size_t)code * 8);
  float4 a = p[0], b = p[1];
  short8 o;
  o[0] = (short)f2bf(a.x); o[1] = (short)f2bf(a.y);
  o[2] = (short)f2bf(a.z); o[3] = (short)f2bf(a.w);
  o[4] = (short)f2bf(b.x); o[5] = (short)f2bf(b.y);
  o[6] = (short)f2bf(b.z); o[7] = (short)f2bf(b.w);
  ((short8*)wb)[idx] = o;
}

// ---- Kernel 3: 256x256 GEMM, BK=64, 8 waves (2Mx4N), A-only LDS (3 slots x 32 KiB,
// st_16x32 swizzle), B direct global->reg. Per group t (slots SC=t%3, SN=(t+1)%3,
// SS=(t+2)%3): W0: issue b23(t)+stageA(t+2), VMC(8), BAR, MFMA aLxb01;
// W1: VMC(4) b23, MFMA aLxb23, ds_read aH; W2: MFMA aHxb01;
// W3: issue b01(t+1), MFMA aHxb23, ds_read aL(t+1) from SN.

#define BAR() __builtin_amdgcn_s_barrier()
#define SB() __builtin_amdgcn_sched_barrier(0)
#define PRIO1() __builtin_amdgcn_s_setprio(1)
#define PRIO0() __builtin_amdgcn_s_setprio(0)
#define LGKM(N_) asm volatile("s_waitcnt lgkmcnt(" #N_ ")" ::: "memory")
#define VMC(N_) asm volatile("s_waitcnt vmcnt(" #N_ ")" ::: "memory")

#define STAGE_A(slot_, h_, kt_) do { \
  _Pragma("unroll") for (int i_ = 0; i_ < 2; ++i_) { \
    const unsigned short* src_ = Ag + (size_t)(sa_roff[i_] + (h_) * 64) * 4096 + (unsigned)((kt_) + sa_koff[i_]); \
    __builtin_amdgcn_global_load_lds((as1_cvoid_p)src_, \
      (as3_void_p)(smem + (slot_) * 32768 + sa_lds[i_] + (h_) * 4096), 16, 0, 0); \
  } } while (0)

// direct B fragment load: half_=0 -> n-frags 0,1 (cols 0..31), half_=1 -> n-frags 2,3
#define LOAD_B(dst_, half_, kt_) \
  _Pragma("unroll") for (int n_ = 0; n_ < 2; ++n_) \
  _Pragma("unroll") for (int kk_ = 0; kk_ < 2; ++kk_) \
    dst_[n_][kk_] = *(const bf16x8*)(Bl + (size_t)((half_) * 2 + n_) * 16 * 4096 + (unsigned)((kt_) + kk_ * 32));

// quarter A-fragment read: q_=0 -> af[0..1], q_=1 -> af[2..3]; ma_ = A half (0/1)
#define LDA_Q(q_, ma_, slot_) \
  _Pragma("unroll") for (int j_ = 0; j_ < 2; ++j_) \
  _Pragma("unroll") for (int kk_ = 0; kk_ < 2; ++kk_) \
    af[(q_) * 2 + j_][kk_] = *(const bf16x8*)(smem + (slot_) * 32768 + aRd + ((ma_) * 4 + (q_) * 2 + j_) * 1024 + kk_ * 16384);

// 8 MFMAs: acc rows base_+q_*2..+1, cols nb_..nb_+1
#define MM_Q(base_, q_, nb_, bfr_) \
  _Pragma("unroll") for (int j_ = 0; j_ < 2; ++j_) \
  _Pragma("unroll") for (int n_ = 0; n_ < 2; ++n_) \
  _Pragma("unroll") for (int kk_ = 0; kk_ < 2; ++kk_) \
    acc[(base_) + (q_) * 2 + j_][(nb_) + n_] = __builtin_amdgcn_mfma_f32_16x16x32_bf16( \
        af[(q_) * 2 + j_][kk_], bfr_[n_][kk_], acc[(base_) + (q_) * 2 + j_][(nb_) + n_], 0, 0, 0);

// MODE: 2=steady (t<=61), 1=t=62 (no stageA), 0=t=63 (no stage, no W3 issues)
#define GROUP(SC_, SN_, SS_, MODE_, KT_) do { \
  BAR(); \
  /* W0: issue b23(t); stage A(t+2); drain stageA(t+1)+b01(t); MFMA aL x b01 */ \
  LOAD_B(bf1, 1, KT_); SB(); \
  if ((MODE_) == 2) { STAGE_A(SS_, 0, (KT_) + 128); STAGE_A(SS_, 1, (KT_) + 128); } \
  SB(); \
  if ((MODE_) == 2) { VMC(8); } else { VMC(4); } \
  BAR(); \
  LGKM(4); SB(); PRIO1(); MM_Q(0, 0, 0, bf0); \
  LGKM(0); SB(); MM_Q(0, 1, 0, bf0); PRIO0(); SB(); \
  /* W1: wait b23; MFMA aL x b23; then ds_read aH(t) */ \
  if ((MODE_) == 2) { VMC(4); } else { VMC(0); } \
  SB(); PRIO1(); MM_Q(0, 0, 2, bf1); MM_Q(0, 1, 2, bf1); PRIO0(); SB(); \
  LDA_Q(0, 1, SC_); SB(); LDA_Q(1, 1, SC_); SB(); \
  /* W2: MFMA aH x b01 */ \
  LGKM(4); SB(); PRIO1(); MM_Q(4, 0, 0, bf0); \
  LGKM(0); SB(); MM_Q(4, 1, 0, bf0); PRIO0(); SB(); \
  /* W3: issue b01(t+1); MFMA aH x b23; ds_read aL(t+1) from SN */ \
  if ((MODE_) >= 1) { LOAD_B(bf0, 0, (KT_) + 64); } \
  SB(); PRIO1(); MM_Q(4, 0, 2, bf1); MM_Q(4, 1, 2, bf1); PRIO0(); SB(); \
  if ((MODE_) >= 1) { LDA_Q(0, 0, SN_); SB(); LDA_Q(1, 0, SN_); } \
  SB(); \
} while (0)

__global__ __launch_bounds__(512) void gemm8_kernel(
    const unsigned short* __restrict__ A,   // bf16 [M][K]
    const unsigned short* __restrict__ B,   // bf16 [N][K]
    const float* __restrict__ scales,
    const float* __restrict__ bias,
    float* __restrict__ C) {
  extern __shared__ char smem[];  // 98304 B: 3 A-slots

  // grid 512 = 32 bm x 16 bn; bijective XCD swizzle (512 % 8 == 0)
  const int bid = blockIdx.x;
  const int swz = (bid & 7) * 64 + (bid >> 3);
  const int bm = swz >> 4;
  const int bn = swz & 15;

  const int tid = threadIdx.x;
  const int w = tid >> 6;
  const int l = tid & 63;
  const int wr = w >> 2;    // 0..1
  const int wcol = w & 3;   // 0..3

  // ---- A staging constants (linear LDS dest, inverse-swizzled global source)
  const int llog = l ^ (((l >> 5) & 1) << 1);
  int sa_roff[2], sa_koff[2], sa_lds[2];
#pragma unroll
  for (int i = 0; i < 2; ++i) {
    int u = w * 2 + i;
    int panel = u >> 3;
    int rbA = (u >> 2) & 1, chA = u & 3;
    sa_roff[i] = rbA * 128 + chA * 16 + (llog >> 2);
    sa_koff[i] = panel * 32 + (llog & 3) * 8;
    sa_lds[i] = panel * 16384 + rbA * 8192 + chA * 1024;
  }

  const unsigned short* Ag = A + (size_t)bm * 256 * 4096;
  // per-lane B base: row = bn*256 + wcol*64 + (l&15), k-chunk (l>>4)*8
  const unsigned short* Bl = B + ((size_t)bn * 256 + wcol * 64 + (l & 15)) * 4096 + ((l >> 4) * 8);

  // ---- A fragment read base (swizzled)
  const int xr = ((l >> 4) * 16) ^ (((l >> 3) & 1) << 5);
  const int aRd = (wr * 128 + (l & 15)) * 64 + xr;

  f32x4 acc[8][4];
#pragma unroll
  for (int m = 0; m < 8; ++m)
#pragma unroll
    for (int n = 0; n < 4; ++n) acc[m][n] = (f32x4){0.f, 0.f, 0.f, 0.f};

  bf16x8 af[4][2], bf0[2][2], bf1[2][2];

  // ---- prologue: stage A(0)->slot0, A(1)->slot1; load b01(0); drain A(0); prime aL(0)
  STAGE_A(0, 0, 0); STAGE_A(0, 1, 0);
  STAGE_A(1, 0, 64); STAGE_A(1, 1, 64);
  LOAD_B(bf0, 0, 0); SB();
  VMC(8);   // 12 outstanding -> drain A(0)x4; leaves {A(1)x4, b01(0)x4} = steady entry
  BAR();
  LDA_Q(0, 0, 0); SB(); LDA_Q(1, 0, 0); SB();   // aL(0): 8 lgkm in flight

  // ---- main loop: 64 K-tiles; slots rotate t%3
  int kt = 0;
  for (int j = 0; j < 20; ++j) {
    GROUP(0, 1, 2, 2, kt);
    GROUP(1, 2, 0, 2, kt + 64);
    GROUP(2, 0, 1, 2, kt + 128);
    kt += 192;
  }
  GROUP(0, 1, 2, 2, 3840);   // t=60
  GROUP(1, 2, 0, 2, 3904);   // t=61 (stages A(63)->slot0)
  GROUP(2, 0, 1, 1, 3968);   // t=62 (no stage; issues b01(63), reads aL(63))
  GROUP(0, 1, 2, 0, 4032);   // t=63
  SB();  // keep epilogue loads out of the counted region

  // ---- epilogue: scale + bias, fp32 store
  const int row0 = bm * 256 + wr * 128 + ((l >> 4) << 2);
  const int col0 = bn * 256 + wcol * 64 + (l & 15);
#pragma unroll
  for (int n = 0; n < 4; ++n) {
    const int col = col0 + n * 16;
    const float s = scales[col];
    const float bv = bias[col];
#pragma unroll
    for (int m = 0; m < 8; ++m) {
      f32x4 v = acc[m][n];
      const int r = row0 + m * 16;
#pragma unroll
      for (int j = 0; j < 4; ++j)
        C[(size_t)(r + j) * 4096 + col] = v[j] * s + bv;
    }
  }
}

extern "C" void kernel_launch(void* const* d_in, const int* in_sizes, int n_in,
                              void* d_out, int out_size, void* d_ws, size_t ws_size,
                              hipStream_t stream) {
  const float* x = (const float*)d_in[0];
  const int* codes = (const int*)d_in[1];
  const float* cb = (const float*)d_in[2];
  const float* scales = (const float*)d_in[3];
  const float* bias = (const float*)d_in[4];
  float* out = (float*)d_out;

  unsigned short* xb = (unsigned short*)d_ws;
  unsigned short* wb = (unsigned short*)((char*)d_ws + (size_t)M_DIM * K_DIM * 2);

  hipFuncSetAttribute((const void*)gemm8_kernel,
                      hipFuncAttributeMaxDynamicSharedMemorySize, 98304);

  cvt_x_kernel<<<4096, 256, 0, stream>>>(x, xb, (M_DIM * K_DIM) / 8);
  dequant_kernel<<<(NOG * NIG) / 256, 256, 0, stream>>>(codes, cb, wb);
  gemm8_kernel<<<dim3((M_DIM / 256) * (N_DIM / 256)), 512, 98304, stream>>>(
      xb, wb, scales, bias, out);
}

// Round 7
// 298.681 us; speedup vs baseline: 1.2488x; 1.2488x over previous
//
#include <hip/hip_runtime.h>
#include <hip/hip_bf16.h>

// QuantizedLinear: out[8192,4096] = x[8192,4096] @ W^T + bias
//   W[n,k] = codebooks[codes[n, k/8]][k%8] * scales[n]  (NCB=1; scale in epilogue)
// Round-7 GEMM: 256x256, BK=64, 8 waves (2Mx4N), mfma_f32_32x32x16_bf16
// (higher MFMA ceiling + 4x fewer MFMA issues than 16x16x32). A+B in LDS,
// 2 slots x 64 KiB, staged by K-PANEL (AP0/BP0/AP1/BP1, 16KB each).
// Per group: 4 windows (k-steps), 2 barriers, VMC(4) at W1/W3 ends,
// counted LGKM against reads issued a window early into ping-pong frag regs.
#define M_DIM 8192
#define N_DIM 4096
#define K_DIM 4096
#define NOG 4096
#define NIG 512

typedef __bf16 bf16x8 __attribute__((ext_vector_type(8)));
typedef float f32x16 __attribute__((ext_vector_type(16)));
typedef short short8 __attribute__((ext_vector_type(8)));

typedef const __attribute__((address_space(1))) void* as1_cvoid_p;
typedef __attribute__((address_space(3))) void* as3_void_p;

__device__ __forceinline__ unsigned short f2bf(float f) {
  union { float f; unsigned u; } c; c.f = f;
  unsigned u = c.u;
  return (unsigned short)((u + 0x7fffu + ((u >> 16) & 1u)) >> 16);
}

// ---- Kernel 1: x f32 -> bf16
__global__ __launch_bounds__(256) void cvt_x_kernel(const float* __restrict__ x,
                                                    unsigned short* __restrict__ xb,
                                                    int n8) {
  int i = blockIdx.x * blockDim.x + threadIdx.x;
  int stride = gridDim.x * blockDim.x;
  for (; i < n8; i += stride) {
    const float4* p = (const float4*)(x) + (size_t)i * 2;
    float4 a = p[0], b = p[1];
    short8 o;
    o[0] = (short)f2bf(a.x); o[1] = (short)f2bf(a.y);
    o[2] = (short)f2bf(a.z); o[3] = (short)f2bf(a.w);
    o[4] = (short)f2bf(b.x); o[5] = (short)f2bf(b.y);
    o[6] = (short)f2bf(b.z); o[7] = (short)f2bf(b.w);
    ((short8*)xb)[i] = o;
  }
}

// ---- Kernel 2: gather-dequant -> bf16 W [N][K]
__global__ __launch_bounds__(256) void dequant_kernel(const int* __restrict__ codes,
                                                      const float* __restrict__ cb,
                                                      unsigned short* __restrict__ wb) {
  int idx = blockIdx.x * blockDim.x + threadIdx.x;
  int code = codes[idx];
  const float4* p = (const float4*)(cb + (size_t)code * 8);
  float4 a = p[0], b = p[1];
  short8 o;
  o[0] = (short)f2bf(a.x); o[1] = (short)f2bf(a.y);
  o[2] = (short)f2bf(a.z); o[3] = (short)f2bf(a.w);
  o[4] = (short)f2bf(b.x); o[5] = (short)f2bf(b.y);
  o[6] = (short)f2bf(b.z); o[7] = (short)f2bf(b.w);
  ((short8*)wb)[idx] = o;
}

// ---- Kernel 3 ----------------------------------------------------------
// LDS map per slot s: A at s*32768, B at 65536 + s*32768. Within each:
// panel p (k 0-31 / 32-63) at p*16384; row r (0..255) at r*64; 16B chunk c,
// stored chunk = logical chunk c ^ ((r>>3)&1)<<1  (bit5 ^= row-bit3 swizzle).
// Stage ops (2 global_load_lds/thread each): W0:AP0(t+1) W1:BP0(t+1)
// W2:AP1(t+1) W3:BP1(t+1), all into slot s^1. VMC(4)+BAR at W1-end (lands
// AP1/BP1(t) for W2/W3 reads) and W3-end (lands AP0/BP0(t+1) for next W0).

#define BAR() __builtin_amdgcn_s_barrier()
#define SB() __builtin_amdgcn_sched_barrier(0)
#define PRIO1() __builtin_amdgcn_s_setprio(1)
#define PRIO0() __builtin_amdgcn_s_setprio(0)
#define LGKM(N_) asm volatile("s_waitcnt lgkmcnt(" #N_ ")" ::: "memory")
#define VMC(N_) asm volatile("s_waitcnt vmcnt(" #N_ ")" ::: "memory")

// stage one 16 KB K-panel (p_) of A (isB_=0) or B (isB_=1), tile slot slot_
#define STAGE_P(G_, isB_, slot_, p_, kt_) do { \
  _Pragma("unroll") for (int i_ = 0; i_ < 2; ++i_) { \
    const unsigned short* src_ = (G_) + (size_t)sp_roff[i_] * 4096 + (unsigned)((kt_) + (p_) * 32) + spk; \
    __builtin_amdgcn_global_load_lds((as1_cvoid_p)src_, \
      (as3_void_p)(smem + (isB_) * 65536 + (slot_) * 32768 + (p_) * 16384 + spd[i_]), 16, 0, 0); \
  } } while (0)

// A fragment reads for k-step ks_ (0..3): 4 x b128 into dst_[0..3]
#define LDA32(dst_, ks_, slot_) \
  _Pragma("unroll") for (int mf_ = 0; mf_ < 4; ++mf_) \
    dst_[mf_] = *(const bf16x8*)(smem + ((unsigned)((slot_) * 32768 + ((ks_) >> 1) * 16384 + mf_ * 2048 + aRd0) ^ (((ks_) & 1) << 5)));

// B fragment reads for k-step ks_: 2 x b128 into dst_[0..1]
#define LDB32(dst_, ks_, slot_) \
  _Pragma("unroll") for (int nf_ = 0; nf_ < 2; ++nf_) \
    dst_[nf_] = *(const bf16x8*)(smem + ((unsigned)(65536 + (slot_) * 32768 + ((ks_) >> 1) * 16384 + nf_ * 2048 + bRd0) ^ (((ks_) & 1) << 5)));

// 8 x mfma_32x32x16: acc[mf][nf] += af[mf] * bf[nf]
#define MFMA8(af_, bf_) \
  _Pragma("unroll") for (int mf_ = 0; mf_ < 4; ++mf_) \
  _Pragma("unroll") for (int nf_ = 0; nf_ < 2; ++nf_) \
    acc[mf_][nf_] = __builtin_amdgcn_mfma_f32_32x32x16_bf16(af_[mf_], bf_[nf_], acc[mf_][nf_], 0, 0, 0);

// MODE 2 = steady (stage tile t+1, VMC(4)); MODE 0 = last group (no stage, VMC(0)@W1)
#define GROUP32(S_, MODE_, KT_) do { \
  /* W0: stage AP0(t+1); read ks0+ks1; MFMA ks0 */ \
  if ((MODE_) == 2) STAGE_P(Ag, 0, (S_) ^ 1, 0, (KT_) + 64); \
  LDA32(afA, 0, S_); LDB32(bfA, 0, S_); SB(); \
  LDA32(afB, 1, S_); LDB32(bfB, 1, S_); SB(); \
  LGKM(6); SB(); PRIO1(); MFMA8(afA, bfA); PRIO0(); SB(); \
  /* W1: stage BP0(t+1); MFMA ks1; land AP1/BP1(t) */ \
  if ((MODE_) == 2) STAGE_P(Bg, 1, (S_) ^ 1, 0, (KT_) + 64); \
  LGKM(0); SB(); PRIO1(); MFMA8(afB, bfB); PRIO0(); SB(); \
  if ((MODE_) == 2) { VMC(4); } else { VMC(0); } \
  BAR(); \
  /* W2: stage AP1(t+1); read ks2+ks3; MFMA ks2 */ \
  if ((MODE_) == 2) STAGE_P(Ag, 0, (S_) ^ 1, 1, (KT_) + 64); \
  LDA32(afA, 2, S_); LDB32(bfA, 2, S_); SB(); \
  LDA32(afB, 3, S_); LDB32(bfB, 3, S_); SB(); \
  LGKM(6); SB(); PRIO1(); MFMA8(afA, bfA); PRIO0(); SB(); \
  /* W3: stage BP1(t+1); MFMA ks3; land AP0/BP0(t+1) */ \
  if ((MODE_) == 2) STAGE_P(Bg, 1, (S_) ^ 1, 1, (KT_) + 64); \
  LGKM(0); SB(); PRIO1(); MFMA8(afB, bfB); PRIO0(); SB(); \
  if ((MODE_) == 2) { VMC(4); BAR(); } \
} while (0)

__global__ __launch_bounds__(512) void gemm8_kernel(
    const unsigned short* __restrict__ A,   // bf16 [M][K]
    const unsigned short* __restrict__ B,   // bf16 [N][K]
    const float* __restrict__ scales,
    const float* __restrict__ bias,
    float* __restrict__ C) {
  extern __shared__ char smem[];  // 131072 B

  // grid 512 = 32 bm x 16 bn; bijective XCD swizzle (512 % 8 == 0)
  const int bid = blockIdx.x;
  const int swz = (bid & 7) * 64 + (bid >> 3);
  const int bm = swz >> 4;
  const int bn = swz & 15;

  const int tid = threadIdx.x;
  const int w = tid >> 6;
  const int l = tid & 63;
  const int wr = w >> 2;    // 0..1 (M half)
  const int wcol = w & 3;   // 0..3 (N quarter)

  // ---- staging constants: dest 16B index n = w*128 + i*64 + l -> row n>>2, chunk n&3
  // source chunk = (l&3) ^ ((l>>5)&1)<<1 (inverse of the bit5^row-bit3 swizzle)
  const int llog3 = (l & 3) ^ (((l >> 5) & 1) << 1);
  const int spk = llog3 * 8;                      // source k elem offset within panel
  int sp_roff[2], spd[2];
#pragma unroll
  for (int i = 0; i < 2; ++i) {
    sp_roff[i] = w * 32 + i * 16 + (l >> 2);      // source/dest row
    spd[i] = (w * 128 + i * 64 + l) * 16;         // linear dest byte within panel
  }

  const unsigned short* Ag = A + (size_t)bm * 256 * 4096;
  const unsigned short* Bg = B + (size_t)bn * 256 * 4096;

  // ---- fragment read bases (swizzled): row*64 + (l>>5)*16 + row-bit3 XOR on bit5
  const int xr0 = ((l >> 5) * 16) + (((l >> 3) & 1) << 5);
  const int aRd0 = (wr * 128 + (l & 31)) * 64 + xr0;
  const int bRd0 = (wcol * 64 + (l & 31)) * 64 + xr0;

  f32x16 acc[4][2];
#pragma unroll
  for (int mf = 0; mf < 4; ++mf)
#pragma unroll
    for (int nf = 0; nf < 2; ++nf)
#pragma unroll
      for (int r = 0; r < 16; ++r) acc[mf][nf][r] = 0.f;

  bf16x8 afA[4], afB[4], bfA[2], bfB[2];

  // ---- prologue: stage tile0 {AP0,BP0,AP1,BP1} -> slot0; drain panel0; BAR
  STAGE_P(Ag, 0, 0, 0, 0); STAGE_P(Bg, 1, 0, 0, 0);
  STAGE_P(Ag, 0, 0, 1, 0); STAGE_P(Bg, 1, 0, 1, 0);
  VMC(4);   // AP0/BP0 resident; [AP1,BP1] in flight = steady entry invariant
  BAR();

  // ---- main loop: 64 K-tiles, slot = t&1
  int kt = 0;
  for (int j = 0; j < 31; ++j) {
    GROUP32(0, 2, kt);
    GROUP32(1, 2, kt + 64);
    kt += 128;
  }
  GROUP32(0, 2, 3968);   // t=62 (stages tile 63 -> slot 1)
  GROUP32(1, 0, 4032);   // t=63 (no stage)

  // ---- epilogue: C/D 32x32 layout col=l&31, row=(reg&3)+8*(reg>>2)+4*(l>>5)
  const int r0 = bm * 256 + wr * 128 + 4 * (l >> 5);
  const int c0 = bn * 256 + wcol * 64 + (l & 31);
#pragma unroll
  for (int nf = 0; nf < 2; ++nf) {
    const int col = c0 + nf * 32;
    const float s = scales[col];
    const float bv = bias[col];
#pragma unroll
    for (int mf = 0; mf < 4; ++mf) {
      f32x16 v = acc[mf][nf];
      const int rb = r0 + mf * 32;
#pragma unroll
      for (int r = 0; r < 16; ++r)
        C[(size_t)(rb + (r & 3) + 8 * (r >> 2)) * 4096 + col] = v[r] * s + bv;
    }
  }
}

extern "C" void kernel_launch(void* const* d_in, const int* in_sizes, int n_in,
                              void* d_out, int out_size, void* d_ws, size_t ws_size,
                              hipStream_t stream) {
  const float* x = (const float*)d_in[0];
  const int* codes = (const int*)d_in[1];
  const float* cb = (const float*)d_in[2];
  const float* scales = (const float*)d_in[3];
  const float* bias = (const float*)d_in[4];
  float* out = (float*)d_out;

  unsigned short* xb = (unsigned short*)d_ws;
  unsigned short* wb = (unsigned short*)((char*)d_ws + (size_t)M_DIM * K_DIM * 2);

  hipFuncSetAttribute((const void*)gemm8_kernel,
                      hipFuncAttributeMaxDynamicSharedMemorySize, 131072);

  cvt_x_kernel<<<4096, 256, 0, stream>>>(x, xb, (M_DIM * K_DIM) / 8);
  dequant_kernel<<<(NOG * NIG) / 256, 256, 0, stream>>>(codes, cb, wb);
  gemm8_kernel<<<dim3((M_DIM / 256) * (N_DIM / 256)), 512, 131072, stream>>>(
      xb, wb, scales, bias, out);
}